// Round 4
// baseline (51897.449 us; speedup 1.0000x reference)
//
#include <hip/hip_runtime.h>
#include <math.h>

// ESN recurrence: x_t = tanh(w_in*u_t + W x_{t-1}); out[t-washout] = c . x_t
// R18 = R16 (8x replicated single-hop tagged-pair exchange, 32.9ms) with
// per-thread 4-STREAM PHASE-STAGGERED polling across DIFFERENT replicas.
// Model (calibrated R15-R17): fabric/MALL RT ~1.4us (R15: +1 serial RT =
// +1.39us/step). Poll loads to one line are MSHR-coalesced per XCD L2
// (FETCH = payload-lines x 8 XCDs/step), so a poll stream samples the LLC
// once per RT; detection quantization ~1.5RT. R17's same-line 3-deep rotation
// was MSHR-merged (all returns = same snapshot) -> no stagger, only s_sleep
// overhead (-7%). Fix: 4 concurrent streams per thread on 4 DIFFERENT replica
// lines (separate MSHRs), initial issues offset by s_sleep(13) (~RT/4); each
// stream self-sustains its phase (reissue-on-return). Sampling cadence
// RT -> RT/4. Sleep-blindness (first ~1us) is off the critical path (gating
// values arrive >=2us into the wait).
// Prediction: detect 1.5RT -> ~0.75RT: 4.02 -> 3.0-3.6us/step (25-30ms),
// FETCH x2-4; NULL (>=32ms) kills the sampling model -> declare the
// cross-XCD visibility floor next round.

#define H_   2048
#define RPB  8          // rows per block
#define NBLK 256
#define NREP 8          // value-buffer replicas
typedef unsigned long long ull;
// ws layout (float idx):
//   [0, 65536)      ull xval[NREP][2][2048]: per-replica, per-parity
//                   (epoch<<32 | value) for each x element. 256 KB.
//   [65536, 67584)  float c (scatter of w_out by mask)
//   [67584, 67584+T*256)  part (per-step per-block partials, plain store)

__global__ void esn_zero(float* __restrict__ p, int n)
{
    int i = blockIdx.x * blockDim.x + threadIdx.x;
    int stride = gridDim.x * blockDim.x;
    for (; i < n; i += stride) p[i] = 0.0f;
}

__global__ __launch_bounds__(1024) void esn_scatter_c(const int* __restrict__ mask,
                                                      const float* __restrict__ w_out,
                                                      float* __restrict__ ws_f, int H)
{
    float* c = ws_f + 65536;
    for (int i = threadIdx.x; i < H; i += blockDim.x)
        atomicAdd(&c[mask[i]], w_out[i]);
}

__global__ __launch_bounds__(256) void esn_run(const float* __restrict__ u,
                                               const float* __restrict__ w_res,
                                               const float* __restrict__ w_in,
                                               float* __restrict__ out,
                                               float* __restrict__ ws_f,
                                               int T, int washout, int use_part)
{
    __shared__ float Wlds[RPB * H_];   // 64 KB
    __shared__ float xs[H_];
    __shared__ float psum[4];

    const int tid  = threadIdx.x;
    const int wave = tid >> 6;
    const int lane = tid & 63;
    const int bid  = blockIdx.x;
    const int r0 = 2 * wave;
    const int grow0 = bid * RPB + r0, grow1 = grow0 + 1;

    {
        const float4* src = (const float4*)(w_res + (size_t)bid * RPB * H_);
        float4* dst = (float4*)Wlds;
        for (int i = tid; i < RPB * H_ / 4; i += 256) dst[i] = src[i];
    }
    float win0 = 0.f, win1 = 0.f, c0 = 0.f, c1 = 0.f;
    if (lane == 0) {
        win0 = w_in[grow0]; win1 = w_in[grow1];
        c0 = ws_f[65536 + grow0]; c1 = ws_f[65536 + grow1];
    }

    ull* xv = (ull*)ws_f;              // [NREP][2][2048]
    float* part = ws_f + 67584;

    const float4* w0p = (const float4*)(Wlds + r0 * H_);
    const float4* w1p = (const float4*)(Wlds + (r0 + 1) * H_);
    const float4* xs4 = (const float4*)xs;

    float u_next = u[0];
    __syncthreads();   // Wlds ready

    for (int k = 0; k < T; ++k) {
        const int par = (k & 1) * 2048;
        // 4 poll streams on 4 distinct replicas (distinct LLC lines -> distinct MSHRs)
        const ull* rp0 = xv + (size_t)(((bid & 7) + 0) & 7) * 4096 + par;
        const ull* rp1 = xv + (size_t)(((bid & 7) + 2) & 7) * 4096 + par;
        const ull* rp2 = xv + (size_t)(((bid & 7) + 4) & 7) * 4096 + par;
        const ull* rp3 = xv + (size_t)(((bid & 7) + 6) & 7) * 4096 + par;
        float uk = u_next;
        if (k + 1 < T) u_next = u[k + 1];

        // ---- stage x_k: batch load, then 4-stream staggered retry on pending ----
        ull pa[8];
#pragma unroll
        for (int i = 0; i < 8; ++i)
            pa[i] = __hip_atomic_load(rp0 + (i << 8) + tid, __ATOMIC_RELAXED,
                                      __HIP_MEMORY_SCOPE_AGENT);
        unsigned pend = 0;
#pragma unroll
        for (int i = 0; i < 8; ++i)
            if ((unsigned)(pa[i] >> 32) != (unsigned)k) pend |= (1u << i);
        if (pend) {
            ull s0[8], s1[8], s2[8], s3[8];
            // stream 0 re-primed now; streams 1..3 issued at ~RT/4 offsets
#pragma unroll
            for (int i = 0; i < 8; ++i)
                if (pend & (1u << i))
                    s0[i] = __hip_atomic_load(rp0 + (i << 8) + tid,
                                              __ATOMIC_RELAXED, __HIP_MEMORY_SCOPE_AGENT);
            __builtin_amdgcn_s_sleep(13);   // ~830 cy ~ RT/4
#pragma unroll
            for (int i = 0; i < 8; ++i)
                if (pend & (1u << i))
                    s1[i] = __hip_atomic_load(rp1 + (i << 8) + tid,
                                              __ATOMIC_RELAXED, __HIP_MEMORY_SCOPE_AGENT);
            __builtin_amdgcn_s_sleep(13);
#pragma unroll
            for (int i = 0; i < 8; ++i)
                if (pend & (1u << i))
                    s2[i] = __hip_atomic_load(rp2 + (i << 8) + tid,
                                              __ATOMIC_RELAXED, __HIP_MEMORY_SCOPE_AGENT);
            __builtin_amdgcn_s_sleep(13);
#pragma unroll
            for (int i = 0; i < 8; ++i)
                if (pend & (1u << i))
                    s3[i] = __hip_atomic_load(rp3 + (i << 8) + tid,
                                              __ATOMIC_RELAXED, __HIP_MEMORY_SCOPE_AGENT);

#define POLL_SLOT(SV, RP)                                                     \
            {                                                                 \
                unsigned np = 0;                                              \
                _Pragma("unroll")                                             \
                for (int i = 0; i < 8; ++i)                                   \
                    if (pend & (1u << i)) {                                   \
                        if ((unsigned)(SV[i] >> 32) == (unsigned)k)           \
                            pa[i] = SV[i];                                    \
                        else                                                  \
                            np |= (1u << i);                                  \
                    }                                                         \
                pend = np;                                                    \
                if (!pend) break;                                             \
                _Pragma("unroll")                                             \
                for (int i = 0; i < 8; ++i)                                   \
                    if (pend & (1u << i))                                     \
                        SV[i] = __hip_atomic_load(RP + (i << 8) + tid,        \
                                                  __ATOMIC_RELAXED,          \
                                                  __HIP_MEMORY_SCOPE_AGENT);  \
            }

            int spins = 0;
            for (;;) {
                POLL_SLOT(s0, rp0)
                POLL_SLOT(s1, rp1)
                POLL_SLOT(s2, rp2)
                POLL_SLOT(s3, rp3)
                if (++spins > 500000) break;   // failsafe
            }
#undef POLL_SLOT
        }
#pragma unroll
        for (int i = 0; i < 8; ++i)
            xs[(i << 8) + tid] = __uint_as_float((unsigned)pa[i]);
        __syncthreads();

        // ---- dot: wave owns rows r0, r0+1 ----
        float4 a0 = {0.f,0.f,0.f,0.f}, a1 = {0.f,0.f,0.f,0.f};
#pragma unroll
        for (int c = 0; c < 8; ++c) {
            float4 xvv = xs4[c * 64 + lane];
            float4 wv0 = w0p[c * 64 + lane];
            float4 wv1 = w1p[c * 64 + lane];
            a0.x = fmaf(wv0.x, xvv.x, a0.x); a0.y = fmaf(wv0.y, xvv.y, a0.y);
            a0.z = fmaf(wv0.z, xvv.z, a0.z); a0.w = fmaf(wv0.w, xvv.w, a0.w);
            a1.x = fmaf(wv1.x, xvv.x, a1.x); a1.y = fmaf(wv1.y, xvv.y, a1.y);
            a1.z = fmaf(wv1.z, xvv.z, a1.z); a1.w = fmaf(wv1.w, xvv.w, a1.w);
        }
        float s0 = (a0.x + a0.y) + (a0.z + a0.w);
        float s1 = (a1.x + a1.y) + (a1.z + a1.w);
#pragma unroll
        for (int d = 1; d < 64; d <<= 1) {
            s0 += __shfl_xor(s0, d);
            s1 += __shfl_xor(s1, d);
        }

        ull p0 = 0, p1 = 0;
        if (lane == 0) {
            float z0 = fmaf(win0, uk, s0);
            float z1 = fmaf(win1, uk, s1);
            z0 = fminf(fmaxf(z0, -15.f), 15.f);
            z1 = fminf(fmaxf(z1, -15.f), 15.f);
            float e0 = __expf(2.f * z0), e1 = __expf(2.f * z1);
            float t0 = (e0 - 1.f) / (e0 + 1.f), t1 = (e1 - 1.f) / (e1 + 1.f);
            p0 = ((ull)(unsigned)(k + 1) << 32) | (ull)__float_as_uint(t0);
            p1 = ((ull)(unsigned)(k + 1) << 32) | (ull)__float_as_uint(t1);
            psum[wave] = c0 * t0 + c1 * t1;
        }
        // broadcast the tagged pairs; lanes 0..7 publish replica 'lane' (R16 form)
        p0 = __shfl(p0, 0, 64);
        p1 = __shfl(p1, 0, 64);
        if (lane < NREP) {
            ull* dpr = xv + (size_t)lane * 4096 + ((k + 1) & 1) * 2048;
            // exchange: commits at the far unit (no writeback lag)
            (void)__hip_atomic_exchange(dpr + grow0, p0, __ATOMIC_RELAXED,
                                        __HIP_MEMORY_SCOPE_AGENT);
            (void)__hip_atomic_exchange(dpr + grow1, p1, __ATOMIC_RELAXED,
                                        __HIP_MEMORY_SCOPE_AGENT);
        }
        __syncthreads();   // psum ready; xs reads done (safe to restage)

        if (tid == 0) {
            float pw = (psum[0] + psum[1]) + (psum[2] + psum[3]);
            if (use_part) part[(size_t)k * NBLK + bid] = pw;
            else if (k >= washout) atomicAdd(&out[k - washout], pw);
        }
    }
}

__global__ __launch_bounds__(256) void esn_reduce(const float* __restrict__ part,
                                                  float* __restrict__ out,
                                                  int out_size, int washout)
{
    int wv = threadIdx.x >> 6, lane = threadIdx.x & 63;
    int t = blockIdx.x * 4 + wv;
    if (t >= out_size) return;
    const float4* p = (const float4*)(part + (size_t)(t + washout) * NBLK);
    float4 v = p[lane];
    float s = (v.x + v.y) + (v.z + v.w);
#pragma unroll
    for (int d = 1; d < 64; d <<= 1) s += __shfl_xor(s, d);
    if (lane == 0) out[t] = s;
}

extern "C" void kernel_launch(void* const* d_in, const int* in_sizes, int n_in,
                              void* d_out, int out_size, void* d_ws, size_t ws_size,
                              hipStream_t stream)
{
    const float* u     = (const float*)d_in[0];
    const float* w_res = (const float*)d_in[1];
    const float* w_in  = (const float*)d_in[2];
    const float* w_out = (const float*)d_in[3];
    const int*   mask  = (const int*)d_in[4];
    int T = in_sizes[0];
    int H = in_sizes[2];
    int washout = T - out_size;
    float* out  = (float*)d_out;
    float* ws_f = (float*)d_ws;

    size_t need = (size_t)(67584 + (size_t)T * NBLK) * 4;
    int use_part = (ws_size >= need) ? 1 : 0;

    hipLaunchKernelGGL(esn_zero, dim3(128), dim3(256), 0, stream, ws_f, 67584);
    if (!use_part)   // direct-atomic fallback needs out pre-zeroed
        hipLaunchKernelGGL(esn_zero, dim3(32), dim3(256), 0, stream, out, out_size);
    hipLaunchKernelGGL(esn_scatter_c, dim3(1), dim3(1024), 0, stream, mask, w_out, ws_f, H);

    void* args[] = { (void*)&u, (void*)&w_res, (void*)&w_in, (void*)&out,
                     (void*)&ws_f, (void*)&T, (void*)&washout, (void*)&use_part };
    hipError_t e = hipLaunchCooperativeKernel((const void*)esn_run,
                                              dim3(NBLK), dim3(256),
                                              args, 0, stream);
    if (e != hipSuccess) {
        hipLaunchKernelGGL(esn_run, dim3(NBLK), dim3(256), 0, stream,
                           u, w_res, w_in, out, ws_f, T, washout, use_part);
    }
    if (use_part)
        hipLaunchKernelGGL(esn_reduce, dim3((out_size + 3) / 4), dim3(256), 0, stream,
                           ws_f + 67584, out, out_size, washout);
}

// Round 5
// 35438.312 us; speedup vs baseline: 1.4644x; 1.4644x over previous
//
#include <hip/hip_runtime.h>
#include <math.h>

// ESN recurrence: x_t = tanh(w_in*u_t + W x_{t-1}); out[t-washout] = c . x_t
// R19 = R16 (8x replicated single-hop tagged-pair exchange, 32.9ms) with the
// PRODUCER PUBLISH DRAIN removed from the critical path.
// Model re-audit (after R16 contention-null, R17/R18 sampling-null): R16's
// step ends xchg -> __syncthreads(); the barrier's implicit s_waitcnt
// vmcnt(0) stalls ALL waves for the exchange's MALL round-trip (~1.4us)
// before the next poll can begin. Chain: drain 1.4 + poll RT 1.4 + compute
// 0.5 = 3.3us ~= measured 4.05 -- closes with no exotic terms.
// Fix: publish LAST in the step body with NO following barrier. The next
// poll batch issues immediately; its first tag check's vmcnt(0) drains the
// (older, issue-ordered) exchanges concurrently with the poll round-trip --
// the drain merges into a RT we pay anyway. Barriers move to B1 (post-poll:
// x_k in regs, xs/psum of k-1 dead) and B2 (post-stage: xs ready). psum ->
// part pipelines one step: tid0 stores part[k-1] between B1 and B2 (psum
// writers of step k write only after B2); epilogue flushes part[T-1].
// Safety: unchanged induction -- seeing all tag-k rows implies every block
// finished publishing k (xchg committed before observable) and each block's
// k-1 xs-reads precede its own k-poll in program order.
// Prediction: per-step 4.02 -> 2.4-3.4us (dur 20-28ms), FETCH ~R16 level;
// neutral (32-34ms) -> drain already hidden -> remaining terms are measured
// fabric RT + compute -> declare floor next round.

#define H_   2048
#define RPB  8          // rows per block
#define NBLK 256
#define NREP 8          // value-buffer replicas
typedef unsigned long long ull;
// ws layout (float idx):
//   [0, 65536)      ull xval[NREP][2][2048]: per-replica, per-parity
//                   (epoch<<32 | value) for each x element. 256 KB.
//   [65536, 67584)  float c (scatter of w_out by mask)
//   [67584, 67584+T*256)  part (per-step per-block partials, plain store)

__global__ void esn_zero(float* __restrict__ p, int n)
{
    int i = blockIdx.x * blockDim.x + threadIdx.x;
    int stride = gridDim.x * blockDim.x;
    for (; i < n; i += stride) p[i] = 0.0f;
}

__global__ __launch_bounds__(1024) void esn_scatter_c(const int* __restrict__ mask,
                                                      const float* __restrict__ w_out,
                                                      float* __restrict__ ws_f, int H)
{
    float* c = ws_f + 65536;
    for (int i = threadIdx.x; i < H; i += blockDim.x)
        atomicAdd(&c[mask[i]], w_out[i]);
}

__global__ __launch_bounds__(256) void esn_run(const float* __restrict__ u,
                                               const float* __restrict__ w_res,
                                               const float* __restrict__ w_in,
                                               float* __restrict__ out,
                                               float* __restrict__ ws_f,
                                               int T, int washout, int use_part)
{
    __shared__ float Wlds[RPB * H_];   // 64 KB
    __shared__ float xs[H_];
    __shared__ float psum[4];

    const int tid  = threadIdx.x;
    const int wave = tid >> 6;
    const int lane = tid & 63;
    const int bid  = blockIdx.x;
    const int r0 = 2 * wave;
    const int grow0 = bid * RPB + r0, grow1 = grow0 + 1;

    {
        const float4* src = (const float4*)(w_res + (size_t)bid * RPB * H_);
        float4* dst = (float4*)Wlds;
        for (int i = tid; i < RPB * H_ / 4; i += 256) dst[i] = src[i];
    }
    float win0 = 0.f, win1 = 0.f, c0 = 0.f, c1 = 0.f;
    if (lane == 0) {
        win0 = w_in[grow0]; win1 = w_in[grow1];
        c0 = ws_f[65536 + grow0]; c1 = ws_f[65536 + grow1];
    }

    ull* xv = (ull*)ws_f;              // [NREP][2][2048]
    float* part = ws_f + 67584;

    const float4* w0p = (const float4*)(Wlds + r0 * H_);
    const float4* w1p = (const float4*)(Wlds + (r0 + 1) * H_);
    const float4* xs4 = (const float4*)xs;

    // this block reads replica (bid & 7) only
    const ull* rbase = xv + (size_t)(bid & (NREP - 1)) * 4096;

    float u_next = u[0];
    __syncthreads();   // Wlds ready

    for (int k = 0; k < T; ++k) {
        const ull* sp = rbase + (k & 1) * 2048;
        float uk = u_next;
        if (k + 1 < T) u_next = u[k + 1];

        // ---- stage x_k: batch load, then PARALLEL-retry sweeps (R16 form).
        // The previous step's exchanges are still in flight here; the first
        // tag check's vmcnt(0) drains them concurrently with this poll RT.
        ull pv[8];
#pragma unroll
        for (int i = 0; i < 8; ++i)
            pv[i] = __hip_atomic_load(sp + (i << 8) + tid, __ATOMIC_RELAXED,
                                      __HIP_MEMORY_SCOPE_AGENT);
        {
            int spins = 0;
            for (;;) {
                unsigned pend = 0;
#pragma unroll
                for (int i = 0; i < 8; ++i)
                    if ((unsigned)(pv[i] >> 32) != (unsigned)k) {
                        pv[i] = __hip_atomic_load(sp + (i << 8) + tid,
                                                  __ATOMIC_RELAXED,
                                                  __HIP_MEMORY_SCOPE_AGENT);
                        pend = 1;
                    }
                if (!pend) break;
                if (++spins > 500000) break; // failsafe
            }
        }
        __syncthreads();   // B1: all threads hold x_k; xs/psum of k-1 dead

        // pipelined readout store for step k-1 (psum writers of step k
        // cannot write until after B2)
        if (tid == 0 && k > 0) {
            float pw = (psum[0] + psum[1]) + (psum[2] + psum[3]);
            if (use_part) part[(size_t)(k - 1) * NBLK + bid] = pw;
            else if (k - 1 >= washout) atomicAdd(&out[k - 1 - washout], pw);
        }

#pragma unroll
        for (int i = 0; i < 8; ++i)
            xs[(i << 8) + tid] = __uint_as_float((unsigned)pv[i]);
        __syncthreads();   // B2: xs ready; psum of k-1 consumed

        // ---- dot: wave owns rows r0, r0+1 ----
        float4 a0 = {0.f,0.f,0.f,0.f}, a1 = {0.f,0.f,0.f,0.f};
#pragma unroll
        for (int c = 0; c < 8; ++c) {
            float4 xvv = xs4[c * 64 + lane];
            float4 wv0 = w0p[c * 64 + lane];
            float4 wv1 = w1p[c * 64 + lane];
            a0.x = fmaf(wv0.x, xvv.x, a0.x); a0.y = fmaf(wv0.y, xvv.y, a0.y);
            a0.z = fmaf(wv0.z, xvv.z, a0.z); a0.w = fmaf(wv0.w, xvv.w, a0.w);
            a1.x = fmaf(wv1.x, xvv.x, a1.x); a1.y = fmaf(wv1.y, xvv.y, a1.y);
            a1.z = fmaf(wv1.z, xvv.z, a1.z); a1.w = fmaf(wv1.w, xvv.w, a1.w);
        }
        float s0 = (a0.x + a0.y) + (a0.z + a0.w);
        float s1 = (a1.x + a1.y) + (a1.z + a1.w);
#pragma unroll
        for (int d = 1; d < 64; d <<= 1) {
            s0 += __shfl_xor(s0, d);
            s1 += __shfl_xor(s1, d);
        }

        ull p0 = 0, p1 = 0;
        if (lane == 0) {
            float z0 = fmaf(win0, uk, s0);
            float z1 = fmaf(win1, uk, s1);
            z0 = fminf(fmaxf(z0, -15.f), 15.f);
            z1 = fminf(fmaxf(z1, -15.f), 15.f);
            float e0 = __expf(2.f * z0), e1 = __expf(2.f * z1);
            float t0 = (e0 - 1.f) / (e0 + 1.f), t1 = (e1 - 1.f) / (e1 + 1.f);
            p0 = ((ull)(unsigned)(k + 1) << 32) | (ull)__float_as_uint(t0);
            p1 = ((ull)(unsigned)(k + 1) << 32) | (ull)__float_as_uint(t1);
            psum[wave] = c0 * t0 + c1 * t1;
        }
        // broadcast the tagged pairs; lanes 0..7 publish replica 'lane'.
        // NO barrier and NO drain after these -- they stay in flight into the
        // next step's poll, whose vmcnt(0) retires them for free.
        p0 = __shfl(p0, 0, 64);
        p1 = __shfl(p1, 0, 64);
        if (lane < NREP) {
            ull* dpr = xv + (size_t)lane * 4096 + ((k + 1) & 1) * 2048;
            (void)__hip_atomic_exchange(dpr + grow0, p0, __ATOMIC_RELAXED,
                                        __HIP_MEMORY_SCOPE_AGENT);
            (void)__hip_atomic_exchange(dpr + grow1, p1, __ATOMIC_RELAXED,
                                        __HIP_MEMORY_SCOPE_AGENT);
        }
    }

    // epilogue: flush readout of step T-1
    __syncthreads();
    if (tid == 0 && T > 0) {
        float pw = (psum[0] + psum[1]) + (psum[2] + psum[3]);
        if (use_part) part[(size_t)(T - 1) * NBLK + bid] = pw;
        else if (T - 1 >= washout) atomicAdd(&out[T - 1 - washout], pw);
    }
}

__global__ __launch_bounds__(256) void esn_reduce(const float* __restrict__ part,
                                                  float* __restrict__ out,
                                                  int out_size, int washout)
{
    int wv = threadIdx.x >> 6, lane = threadIdx.x & 63;
    int t = blockIdx.x * 4 + wv;
    if (t >= out_size) return;
    const float4* p = (const float4*)(part + (size_t)(t + washout) * NBLK);
    float4 v = p[lane];
    float s = (v.x + v.y) + (v.z + v.w);
#pragma unroll
    for (int d = 1; d < 64; d <<= 1) s += __shfl_xor(s, d);
    if (lane == 0) out[t] = s;
}

extern "C" void kernel_launch(void* const* d_in, const int* in_sizes, int n_in,
                              void* d_out, int out_size, void* d_ws, size_t ws_size,
                              hipStream_t stream)
{
    const float* u     = (const float*)d_in[0];
    const float* w_res = (const float*)d_in[1];
    const float* w_in  = (const float*)d_in[2];
    const float* w_out = (const float*)d_in[3];
    const int*   mask  = (const int*)d_in[4];
    int T = in_sizes[0];
    int H = in_sizes[2];
    int washout = T - out_size;
    float* out  = (float*)d_out;
    float* ws_f = (float*)d_ws;

    size_t need = (size_t)(67584 + (size_t)T * NBLK) * 4;
    int use_part = (ws_size >= need) ? 1 : 0;

    hipLaunchKernelGGL(esn_zero, dim3(128), dim3(256), 0, stream, ws_f, 67584);
    if (!use_part)   // direct-atomic fallback needs out pre-zeroed
        hipLaunchKernelGGL(esn_zero, dim3(32), dim3(256), 0, stream, out, out_size);
    hipLaunchKernelGGL(esn_scatter_c, dim3(1), dim3(1024), 0, stream, mask, w_out, ws_f, H);

    void* args[] = { (void*)&u, (void*)&w_res, (void*)&w_in, (void*)&out,
                     (void*)&ws_f, (void*)&T, (void*)&washout, (void*)&use_part };
    hipError_t e = hipLaunchCooperativeKernel((const void*)esn_run,
                                              dim3(NBLK), dim3(256),
                                              args, 0, stream);
    if (e != hipSuccess) {
        hipLaunchKernelGGL(esn_run, dim3(NBLK), dim3(256), 0, stream,
                           u, w_res, w_in, out, ws_f, T, washout, use_part);
    }
    if (use_part)
        hipLaunchKernelGGL(esn_reduce, dim3((out_size + 3) / 4), dim3(256), 0, stream,
                           ws_f + 67584, out, out_size, washout);
}

// Round 7
// 35026.917 us; speedup vs baseline: 1.4816x; 1.0117x over previous
//
#include <hip/hip_runtime.h>
#include <math.h>

// ESN recurrence: x_t = tanh(w_in*u_t + W x_{t-1}); out[t-washout] = c . x_t
// R21 = R20 resubmitted verbatim (previous bench died to "MI355X container
// failed twice" -- infra, no kernel verdict). Audit found no deadlock/hang
// hazard: poll failsafe intact, induction preserved, launch path unchanged.
//
// R20 = R16 (8x replicated single-hop tagged-pair exchange, 32.9ms BEST) with
// publish moved to step END (no trailing barrier) and the psum/part store
// pipelined one step WITHOUT R19's store-before-barrier bug.
// R19 post-mortem: its 2.3ms loss is explained by tid0's part[k-1] store
// placed between B1 and B2 -- the compiler's vmcnt(0)-before-s_barrier made
// wave0 (hence all waves) eat the store ack (~0.5-0.7us) EVERY step. The
// publish-drain theory was never cleanly tested.
// R16 critical path: xchg -> B2 implicit vmcnt(0) waits the full atomic-RMW
// round trip (~1.4us) -> poll sweep (~0.7-1.0) -> compute (~0.5) = 3.6-4.0us
// (measured 4.02). In publish-last form the poll's own vmcnt(0) subsumes the
// older xchgs (issue-ordered counter) -> drain overlaps sampling, saving
// ~0.5-0.7us/step.
// Race-free psum pipeline: writers update psum after B2(k); tid0 reads psum
// into REGS between B1(k+1) and B2(k+1) (barrier-separated from both the
// k-writes and k+1-writes); the part[k-1] global store issues AFTER B2 where
// its ack drains under the dot + next poll. Epilogue flushes part[T-1].
// Safety induction unchanged: observing all tag-k rows implies every block
// published k, hence consumed x_{k-1}; B1 orders each block's own xs reuse.
// Prediction: 4.02 -> 3.3-3.6us/step (27-29.5ms), FETCH/WRITE ~R16;
// neutral (32-34ms) -> drain already hidden -> declare cross-XCD latency
// floor: commit 0.7 + sample 0.7-1.4 + compute 0.5 + jitter ~1 = 4us.

#define H_   2048
#define RPB  8          // rows per block
#define NBLK 256
#define NREP 8          // value-buffer replicas
typedef unsigned long long ull;
// ws layout (float idx):
//   [0, 65536)      ull xval[NREP][2][2048]: per-replica, per-parity
//                   (epoch<<32 | value) for each x element. 256 KB.
//   [65536, 67584)  float c (scatter of w_out by mask)
//   [67584, 67584+T*256)  part (per-step per-block partials, plain store)

__global__ void esn_zero(float* __restrict__ p, int n)
{
    int i = blockIdx.x * blockDim.x + threadIdx.x;
    int stride = gridDim.x * blockDim.x;
    for (; i < n; i += stride) p[i] = 0.0f;
}

__global__ __launch_bounds__(1024) void esn_scatter_c(const int* __restrict__ mask,
                                                      const float* __restrict__ w_out,
                                                      float* __restrict__ ws_f, int H)
{
    float* c = ws_f + 65536;
    for (int i = threadIdx.x; i < H; i += blockDim.x)
        atomicAdd(&c[mask[i]], w_out[i]);
}

__global__ __launch_bounds__(256) void esn_run(const float* __restrict__ u,
                                               const float* __restrict__ w_res,
                                               const float* __restrict__ w_in,
                                               float* __restrict__ out,
                                               float* __restrict__ ws_f,
                                               int T, int washout, int use_part)
{
    __shared__ float Wlds[RPB * H_];   // 64 KB
    __shared__ float xs[H_];
    __shared__ float psum[4];

    const int tid  = threadIdx.x;
    const int wave = tid >> 6;
    const int lane = tid & 63;
    const int bid  = blockIdx.x;
    const int r0 = 2 * wave;
    const int grow0 = bid * RPB + r0, grow1 = grow0 + 1;

    {
        const float4* src = (const float4*)(w_res + (size_t)bid * RPB * H_);
        float4* dst = (float4*)Wlds;
        for (int i = tid; i < RPB * H_ / 4; i += 256) dst[i] = src[i];
    }
    float win0 = 0.f, win1 = 0.f, c0 = 0.f, c1 = 0.f;
    if (lane == 0) {
        win0 = w_in[grow0]; win1 = w_in[grow1];
        c0 = ws_f[65536 + grow0]; c1 = ws_f[65536 + grow1];
    }

    ull* xv = (ull*)ws_f;              // [NREP][2][2048]
    float* part = ws_f + 67584;

    const float4* w0p = (const float4*)(Wlds + r0 * H_);
    const float4* w1p = (const float4*)(Wlds + (r0 + 1) * H_);
    const float4* xs4 = (const float4*)xs;

    // this block reads replica (bid & 7) only
    const ull* rbase = xv + (size_t)(bid & (NREP - 1)) * 4096;

    float u_next = u[0];
    __syncthreads();   // Wlds ready

    for (int k = 0; k < T; ++k) {
        const ull* sp = rbase + (k & 1) * 2048;
        float uk = u_next;
        if (k + 1 < T) u_next = u[k + 1];

        // ---- stage x_k: batch load, then PARALLEL-retry sweeps (R16 form).
        // Step k-1's xchgs (and tid0's part store) are still in flight; each
        // sweep's vmcnt(0) retires them concurrently with the poll RT.
        ull pv[8];
#pragma unroll
        for (int i = 0; i < 8; ++i)
            pv[i] = __hip_atomic_load(sp + (i << 8) + tid, __ATOMIC_RELAXED,
                                      __HIP_MEMORY_SCOPE_AGENT);
        {
            int spins = 0;
            for (;;) {
                unsigned pend = 0;
#pragma unroll
                for (int i = 0; i < 8; ++i)
                    if ((unsigned)(pv[i] >> 32) != (unsigned)k) {
                        pv[i] = __hip_atomic_load(sp + (i << 8) + tid,
                                                  __ATOMIC_RELAXED,
                                                  __HIP_MEMORY_SCOPE_AGENT);
                        pend = 1;
                    }
                if (!pend) break;
                if (++spins > 500000) break; // failsafe
            }
        }
        __syncthreads();   // B1: everyone holds x_k; psum[k-1] final; xs dead

        // tid0: capture psum[k-1] into regs BETWEEN B1 and B2 -- barrier-
        // separated from step-k-1 writes (before B1) and step-k writes
        // (after B2 + dot). Store issues after B2 (ack drains under compute).
        float pw = 0.f;
        if (tid == 0 && k > 0)
            pw = (psum[0] + psum[1]) + (psum[2] + psum[3]);

#pragma unroll
        for (int i = 0; i < 8; ++i)
            xs[(i << 8) + tid] = __uint_as_float((unsigned)pv[i]);
        __syncthreads();   // B2: xs ready

        if (tid == 0 && k > 0) {
            if (use_part) part[(size_t)(k - 1) * NBLK + bid] = pw;
            else if (k - 1 >= washout) atomicAdd(&out[k - 1 - washout], pw);
        }

        // ---- dot: wave owns rows r0, r0+1 ----
        float4 a0 = {0.f,0.f,0.f,0.f}, a1 = {0.f,0.f,0.f,0.f};
#pragma unroll
        for (int c = 0; c < 8; ++c) {
            float4 xvv = xs4[c * 64 + lane];
            float4 wv0 = w0p[c * 64 + lane];
            float4 wv1 = w1p[c * 64 + lane];
            a0.x = fmaf(wv0.x, xvv.x, a0.x); a0.y = fmaf(wv0.y, xvv.y, a0.y);
            a0.z = fmaf(wv0.z, xvv.z, a0.z); a0.w = fmaf(wv0.w, xvv.w, a0.w);
            a1.x = fmaf(wv1.x, xvv.x, a1.x); a1.y = fmaf(wv1.y, xvv.y, a1.y);
            a1.z = fmaf(wv1.z, xvv.z, a1.z); a1.w = fmaf(wv1.w, xvv.w, a1.w);
        }
        float s0 = (a0.x + a0.y) + (a0.z + a0.w);
        float s1 = (a1.x + a1.y) + (a1.z + a1.w);
#pragma unroll
        for (int d = 1; d < 64; d <<= 1) {
            s0 += __shfl_xor(s0, d);
            s1 += __shfl_xor(s1, d);
        }

        ull p0 = 0, p1 = 0;
        if (lane == 0) {
            float z0 = fmaf(win0, uk, s0);
            float z1 = fmaf(win1, uk, s1);
            z0 = fminf(fmaxf(z0, -15.f), 15.f);
            z1 = fminf(fmaxf(z1, -15.f), 15.f);
            float e0 = __expf(2.f * z0), e1 = __expf(2.f * z1);
            float t0 = (e0 - 1.f) / (e0 + 1.f), t1 = (e1 - 1.f) / (e1 + 1.f);
            p0 = ((ull)(unsigned)(k + 1) << 32) | (ull)__float_as_uint(t0);
            p1 = ((ull)(unsigned)(k + 1) << 32) | (ull)__float_as_uint(t1);
            psum[wave] = c0 * t0 + c1 * t1;
        }
        // broadcast tagged pairs; lanes 0..7 publish replica 'lane'.
        // NO barrier and NO drain after these: they stay in flight into the
        // next step's poll, whose vmcnt(0) retires them for free.
        p0 = __shfl(p0, 0, 64);
        p1 = __shfl(p1, 0, 64);
        if (lane < NREP) {
            ull* dpr = xv + (size_t)lane * 4096 + ((k + 1) & 1) * 2048;
            (void)__hip_atomic_exchange(dpr + grow0, p0, __ATOMIC_RELAXED,
                                        __HIP_MEMORY_SCOPE_AGENT);
            (void)__hip_atomic_exchange(dpr + grow1, p1, __ATOMIC_RELAXED,
                                        __HIP_MEMORY_SCOPE_AGENT);
        }
        __builtin_amdgcn_sched_barrier(0);  // pin publishes before backedge
    }

    // epilogue: flush readout of step T-1
    __syncthreads();
    if (tid == 0 && T > 0) {
        float pw = (psum[0] + psum[1]) + (psum[2] + psum[3]);
        if (use_part) part[(size_t)(T - 1) * NBLK + bid] = pw;
        else if (T - 1 >= washout) atomicAdd(&out[T - 1 - washout], pw);
    }
}

__global__ __launch_bounds__(256) void esn_reduce(const float* __restrict__ part,
                                                  float* __restrict__ out,
                                                  int out_size, int washout)
{
    int wv = threadIdx.x >> 6, lane = threadIdx.x & 63;
    int t = blockIdx.x * 4 + wv;
    if (t >= out_size) return;
    const float4* p = (const float4*)(part + (size_t)(t + washout) * NBLK);
    float4 v = p[lane];
    float s = (v.x + v.y) + (v.z + v.w);
#pragma unroll
    for (int d = 1; d < 64; d <<= 1) s += __shfl_xor(s, d);
    if (lane == 0) out[t] = s;
}

extern "C" void kernel_launch(void* const* d_in, const int* in_sizes, int n_in,
                              void* d_out, int out_size, void* d_ws, size_t ws_size,
                              hipStream_t stream)
{
    const float* u     = (const float*)d_in[0];
    const float* w_res = (const float*)d_in[1];
    const float* w_in  = (const float*)d_in[2];
    const float* w_out = (const float*)d_in[3];
    const int*   mask  = (const int*)d_in[4];
    int T = in_sizes[0];
    int H = in_sizes[2];
    int washout = T - out_size;
    float* out  = (float*)d_out;
    float* ws_f = (float*)d_ws;

    size_t need = (size_t)(67584 + (size_t)T * NBLK) * 4;
    int use_part = (ws_size >= need) ? 1 : 0;

    hipLaunchKernelGGL(esn_zero, dim3(128), dim3(256), 0, stream, ws_f, 67584);
    if (!use_part)   // direct-atomic fallback needs out pre-zeroed
        hipLaunchKernelGGL(esn_zero, dim3(32), dim3(256), 0, stream, out, out_size);
    hipLaunchKernelGGL(esn_scatter_c, dim3(1), dim3(1024), 0, stream, mask, w_out, ws_f, H);

    void* args[] = { (void*)&u, (void*)&w_res, (void*)&w_in, (void*)&out,
                     (void*)&ws_f, (void*)&T, (void*)&washout, (void*)&use_part };
    hipError_t e = hipLaunchCooperativeKernel((const void*)esn_run,
                                              dim3(NBLK), dim3(256),
                                              args, 0, stream);
    if (e != hipSuccess) {
        hipLaunchKernelGGL(esn_run, dim3(NBLK), dim3(256), 0, stream,
                           u, w_res, w_in, out, ws_f, T, washout, use_part);
    }
    if (use_part)
        hipLaunchKernelGGL(esn_reduce, dim3((out_size + 3) / 4), dim3(256), 0, stream,
                           ws_f + 67584, out, out_size, washout);
}

// Round 8
// 32825.491 us; speedup vs baseline: 1.5810x; 1.0671x over previous
//
#include <hip/hip_runtime.h>
#include <math.h>

// ESN recurrence: x_t = tanh(w_in*u_t + W x_{t-1}); out[t-washout] = c . x_t
// R22 = R16 VERBATIM (the measured optimum, 32.9ms) -- final revert.
// Eight bracketing experiments (R10-R21) all neutral-or-worse vs this form:
//   R15 flag-split: +1.75us/step (2 extra LLC hops; calibrates RT~1.4us)
//   R16 8x replication: neutral (poller contention falsified)
//   R17 same-line 3-deep: MSHR-merged, -7% (pacing overhead)
//   R18 cross-replica 4-stream: -40% (sampling-cadence falsified)
//   R19/R21 publish-last drain overlap: -1..-7% (vmcnt is issue-ordered;
//     poll wait = max(xchg,poll) returns -- no slack existed)
// Remaining 4.0us/step = device-wide all-to-all visibility through the
// non-coherent-L2 / LLC fabric: commit 0.7-1.4 + tail-of-max detection over
// 256x256 producer-consumer pairs 1.4-2 + compute/barriers 0.6. W (16MB)
// only fits in >=128 CUs' aggregate LDS -> multi-XCD forced -> LLC is the
// only coherence point. Recurrence is non-associative -> no time-parallel
// reformulation. This is the latency floor for this op on this fabric.
// Prediction: 32.8-33.3ms, FETCH ~1.2e6 KB, WRITE ~4.26e6 KB.

#define H_   2048
#define RPB  8          // rows per block
#define NBLK 256
#define NREP 8          // value-buffer replicas
typedef unsigned long long ull;
// ws layout (float idx):
//   [0, 65536)      ull xval[NREP][2][2048]: per-replica, per-parity
//                   (epoch<<32 | value) for each x element. 256 KB.
//   [65536, 67584)  float c (scatter of w_out by mask)
//   [67584, 67584+T*256)  part (per-step per-block partials, plain store)

__global__ void esn_zero(float* __restrict__ p, int n)
{
    int i = blockIdx.x * blockDim.x + threadIdx.x;
    int stride = gridDim.x * blockDim.x;
    for (; i < n; i += stride) p[i] = 0.0f;
}

__global__ __launch_bounds__(1024) void esn_scatter_c(const int* __restrict__ mask,
                                                      const float* __restrict__ w_out,
                                                      float* __restrict__ ws_f, int H)
{
    float* c = ws_f + 65536;
    for (int i = threadIdx.x; i < H; i += blockDim.x)
        atomicAdd(&c[mask[i]], w_out[i]);
}

__global__ __launch_bounds__(256) void esn_run(const float* __restrict__ u,
                                               const float* __restrict__ w_res,
                                               const float* __restrict__ w_in,
                                               float* __restrict__ out,
                                               float* __restrict__ ws_f,
                                               int T, int washout, int use_part)
{
    __shared__ float Wlds[RPB * H_];   // 64 KB
    __shared__ float xs[H_];
    __shared__ float psum[4];

    const int tid  = threadIdx.x;
    const int wave = tid >> 6;
    const int lane = tid & 63;
    const int bid  = blockIdx.x;
    const int r0 = 2 * wave;
    const int grow0 = bid * RPB + r0, grow1 = grow0 + 1;

    {
        const float4* src = (const float4*)(w_res + (size_t)bid * RPB * H_);
        float4* dst = (float4*)Wlds;
        for (int i = tid; i < RPB * H_ / 4; i += 256) dst[i] = src[i];
    }
    float win0 = 0.f, win1 = 0.f, c0 = 0.f, c1 = 0.f;
    if (lane == 0) {
        win0 = w_in[grow0]; win1 = w_in[grow1];
        c0 = ws_f[65536 + grow0]; c1 = ws_f[65536 + grow1];
    }

    ull* xv = (ull*)ws_f;              // [NREP][2][2048]
    float* part = ws_f + 67584;

    const float4* w0p = (const float4*)(Wlds + r0 * H_);
    const float4* w1p = (const float4*)(Wlds + (r0 + 1) * H_);
    const float4* xs4 = (const float4*)xs;

    // this block reads replica (bid & 7) only
    const ull* rbase = xv + (size_t)(bid & (NREP - 1)) * 4096;

    float u_next = u[0];
    __syncthreads();   // Wlds ready

    for (int k = 0; k < T; ++k) {
        const ull* sp = rbase + (k & 1) * 2048;
        float uk = u_next;
        if (k + 1 < T) u_next = u[k + 1];

        // ---- stage x_k: batch load, then PARALLEL-retry sweeps ----
        ull pv[8];
#pragma unroll
        for (int i = 0; i < 8; ++i)
            pv[i] = __hip_atomic_load(sp + (i << 8) + tid, __ATOMIC_RELAXED,
                                      __HIP_MEMORY_SCOPE_AGENT);
        {
            int spins = 0;
            for (;;) {
                unsigned pend = 0;
#pragma unroll
                for (int i = 0; i < 8; ++i)
                    if ((unsigned)(pv[i] >> 32) != (unsigned)k) {
                        pv[i] = __hip_atomic_load(sp + (i << 8) + tid,
                                                  __ATOMIC_RELAXED,
                                                  __HIP_MEMORY_SCOPE_AGENT);
                        pend = 1;
                    }
                if (!pend) break;
                if (++spins > 500000) break; // failsafe
            }
        }
#pragma unroll
        for (int i = 0; i < 8; ++i)
            xs[(i << 8) + tid] = __uint_as_float((unsigned)pv[i]);
        __syncthreads();

        // ---- dot: wave owns rows r0, r0+1 ----
        float4 a0 = {0.f,0.f,0.f,0.f}, a1 = {0.f,0.f,0.f,0.f};
#pragma unroll
        for (int c = 0; c < 8; ++c) {
            float4 xvv = xs4[c * 64 + lane];
            float4 wv0 = w0p[c * 64 + lane];
            float4 wv1 = w1p[c * 64 + lane];
            a0.x = fmaf(wv0.x, xvv.x, a0.x); a0.y = fmaf(wv0.y, xvv.y, a0.y);
            a0.z = fmaf(wv0.z, xvv.z, a0.z); a0.w = fmaf(wv0.w, xvv.w, a0.w);
            a1.x = fmaf(wv1.x, xvv.x, a1.x); a1.y = fmaf(wv1.y, xvv.y, a1.y);
            a1.z = fmaf(wv1.z, xvv.z, a1.z); a1.w = fmaf(wv1.w, xvv.w, a1.w);
        }
        float s0 = (a0.x + a0.y) + (a0.z + a0.w);
        float s1 = (a1.x + a1.y) + (a1.z + a1.w);
#pragma unroll
        for (int d = 1; d < 64; d <<= 1) {
            s0 += __shfl_xor(s0, d);
            s1 += __shfl_xor(s1, d);
        }

        ull p0 = 0, p1 = 0;
        if (lane == 0) {
            float z0 = fmaf(win0, uk, s0);
            float z1 = fmaf(win1, uk, s1);
            z0 = fminf(fmaxf(z0, -15.f), 15.f);
            z1 = fminf(fmaxf(z1, -15.f), 15.f);
            float e0 = __expf(2.f * z0), e1 = __expf(2.f * z1);
            float t0 = (e0 - 1.f) / (e0 + 1.f), t1 = (e1 - 1.f) / (e1 + 1.f);
            p0 = ((ull)(unsigned)(k + 1) << 32) | (ull)__float_as_uint(t0);
            p1 = ((ull)(unsigned)(k + 1) << 32) | (ull)__float_as_uint(t1);
            psum[wave] = c0 * t0 + c1 * t1;
        }
        // broadcast the tagged pairs; lanes 0..7 publish replica 'lane'
        p0 = __shfl(p0, 0, 64);
        p1 = __shfl(p1, 0, 64);
        if (lane < NREP) {
            ull* dpr = xv + (size_t)lane * 4096 + ((k + 1) & 1) * 2048;
            // exchange: commits at the far unit (no writeback lag)
            (void)__hip_atomic_exchange(dpr + grow0, p0, __ATOMIC_RELAXED,
                                        __HIP_MEMORY_SCOPE_AGENT);
            (void)__hip_atomic_exchange(dpr + grow1, p1, __ATOMIC_RELAXED,
                                        __HIP_MEMORY_SCOPE_AGENT);
        }
        __syncthreads();   // psum ready; xs reads done (safe to restage)

        if (tid == 0) {
            float pw = (psum[0] + psum[1]) + (psum[2] + psum[3]);
            if (use_part) part[(size_t)k * NBLK + bid] = pw;
            else if (k >= washout) atomicAdd(&out[k - washout], pw);
        }
    }
}

__global__ __launch_bounds__(256) void esn_reduce(const float* __restrict__ part,
                                                  float* __restrict__ out,
                                                  int out_size, int washout)
{
    int wv = threadIdx.x >> 6, lane = threadIdx.x & 63;
    int t = blockIdx.x * 4 + wv;
    if (t >= out_size) return;
    const float4* p = (const float4*)(part + (size_t)(t + washout) * NBLK);
    float4 v = p[lane];
    float s = (v.x + v.y) + (v.z + v.w);
#pragma unroll
    for (int d = 1; d < 64; d <<= 1) s += __shfl_xor(s, d);
    if (lane == 0) out[t] = s;
}

extern "C" void kernel_launch(void* const* d_in, const int* in_sizes, int n_in,
                              void* d_out, int out_size, void* d_ws, size_t ws_size,
                              hipStream_t stream)
{
    const float* u     = (const float*)d_in[0];
    const float* w_res = (const float*)d_in[1];
    const float* w_in  = (const float*)d_in[2];
    const float* w_out = (const float*)d_in[3];
    const int*   mask  = (const int*)d_in[4];
    int T = in_sizes[0];
    int H = in_sizes[2];
    int washout = T - out_size;
    float* out  = (float*)d_out;
    float* ws_f = (float*)d_ws;

    size_t need = (size_t)(67584 + (size_t)T * NBLK) * 4;
    int use_part = (ws_size >= need) ? 1 : 0;

    hipLaunchKernelGGL(esn_zero, dim3(128), dim3(256), 0, stream, ws_f, 67584);
    if (!use_part)   // direct-atomic fallback needs out pre-zeroed
        hipLaunchKernelGGL(esn_zero, dim3(32), dim3(256), 0, stream, out, out_size);
    hipLaunchKernelGGL(esn_scatter_c, dim3(1), dim3(1024), 0, stream, mask, w_out, ws_f, H);

    void* args[] = { (void*)&u, (void*)&w_res, (void*)&w_in, (void*)&out,
                     (void*)&ws_f, (void*)&T, (void*)&washout, (void*)&use_part };
    hipError_t e = hipLaunchCooperativeKernel((const void*)esn_run,
                                              dim3(NBLK), dim3(256),
                                              args, 0, stream);
    if (e != hipSuccess) {
        hipLaunchKernelGGL(esn_run, dim3(NBLK), dim3(256), 0, stream,
                           u, w_res, w_in, out, ws_f, T, washout, use_part);
    }
    if (use_part)
        hipLaunchKernelGGL(esn_reduce, dim3((out_size + 3) / 4), dim3(256), 0, stream,
                           ws_f + 67584, out, out_size, washout);
}